// Round 5
// baseline (127.021 us; speedup 1.0000x reference)
//
#include <hip/hip_runtime.h>

#define MT_EPS 1e-8f
#define TCHUNK 32   // triangles per block chunk (LDS-staged, 48B each)

// Per-triangle precompute: fold f=1/det, v1 offset, validity, and EPS into
// 10 affine coefficients (3x float4 = 48B stride):
//   u  = cu . (px,py,1)
//   v  = cv . (px,py,1)
//   tm = t-EPS = ct . (px,py,pz,1)     (hit test: tm >= 0)
//   w  = 1-(u+v) computed in-kernel
// Layout: c0 = (cu_x, cu_y, cu_0, cv_x)
//         c1 = (cv_y, cv_0, ct_x, ct_y)
//         c2 = (ct_z, ct_0-EPS, pad, pad)
__global__ __launch_bounds__(256) void mt_precompute(
    const float* __restrict__ v1, const float* __restrict__ v2,
    const float* __restrict__ v3, float4* __restrict__ coef, int F)
{
    int f = blockIdx.x * 256 + threadIdx.x;
    if (f >= F) return;
    float v1x = v1[3*f+0], v1y = v1[3*f+1], v1z = v1[3*f+2];
    float v2x = v2[3*f+0], v2y = v2[3*f+1], v2z = v2[3*f+2];
    float v3x = v3[3*f+0], v3y = v3[3*f+1], v3z = v3[3*f+2];
    float e1x = v2x - v1x, e1y = v2y - v1y, e1z = v2z - v1z;
    float e2x = v3x - v1x, e2y = v3y - v1y, e2z = v3z - v1z;
    // h = cross(d, e2), d=(0,0,1) -> (-e2y, e2x, 0)
    float hx = -e2y, hy = e2x;
    float a = e1x * hx + e1y * hy;                       // determinant
    float fi = (fabsf(a) > MT_EPS) ? (1.0f / a) : 0.0f;  // invalid -> zero coefs -> tm=-EPS -> miss
    float cux = fi * hx, cuy = fi * hy;
    float cu0 = -(v1x * cux + v1y * cuy);
    float cvx = fi * e1y, cvy = -fi * e1x;
    float cv0 = -(v1x * cvx + v1y * cvy);
    float nx = e1y * e2z - e1z * e2y;
    float ny = e1z * e2x - e1x * e2z;
    float nz = e1x * e2y - e1y * e2x;
    float ctx = fi * nx, cty = fi * ny, ctz = fi * nz;
    float ct0 = -(v1x * ctx + v1y * cty + v1z * ctz) - MT_EPS;
    coef[3*f+0] = make_float4(cux, cuy, cu0, cvx);
    coef[3*f+1] = make_float4(cvy, cv0, ctx, cty);
    coef[3*f+2] = make_float4(ctz, ct0, 0.0f, 0.0f);
}

// 8 points/thread, TCHUNK triangles staged in LDS per block.
// R4 diagnosis: 3 uniform ds_reads per 4 tests saturated the per-CU LDS pipe
// (~0.92 util) pinning VALUBusy at 72%. 8 pts/thread halves ds-rate per test
// (3 ds per 104 VALU -> ~0.46 util) and doubles ILP chains.
// Per test: 7 FMA + add + sub + min3 + min + ashr + add = 13 VALU.
// Miss-count trick: cnt += sign(m) as -1 per miss; hits = TCHUNK + cnt.
__global__ __launch_bounds__(256, 6) void mt_count8(
    const float4* __restrict__ coef, const float* __restrict__ pts,
    float* __restrict__ out, int npts, int F)
{
    __shared__ float4 scoef[TCHUNK * 3];   // 1.5 KB

    int tid = blockIdx.x * 256 + threadIdx.x;
    int p0 = tid * 8;
    bool live = (p0 < npts);

    float px[8], py[8], pz[8];
    if (live) {
        const float4* pv = (const float4*)(pts + (size_t)p0 * 3);
        float4 a = pv[0], b = pv[1], c = pv[2];
        float4 d = pv[3], e = pv[4], g = pv[5];
        px[0]=a.x; py[0]=a.y; pz[0]=a.z;
        px[1]=a.w; py[1]=b.x; pz[1]=b.y;
        px[2]=b.z; py[2]=b.w; pz[2]=c.x;
        px[3]=c.y; py[3]=c.z; pz[3]=c.w;
        px[4]=d.x; py[4]=d.y; pz[4]=d.z;
        px[5]=d.w; py[5]=e.x; pz[5]=e.y;
        px[6]=e.z; py[6]=e.w; pz[6]=g.x;
        px[7]=g.y; py[7]=g.z; pz[7]=g.w;
    } else {
        #pragma unroll
        for (int k = 0; k < 8; ++k) { px[k]=0; py[k]=0; pz[k]=0; }
    }

    // Stage coefficient chunk: TCHUNK*3 = 96 float4 (zero-pad past F).
    if (threadIdx.x < TCHUNK * 3) {
        int gidx = blockIdx.y * (TCHUNK * 3) + threadIdx.x;
        scoef[threadIdx.x] = (gidx < 3 * F) ? coef[gidx]
                                            : make_float4(0.f, 0.f, 0.f, 0.f);
    }
    __syncthreads();

    int cnt[8];
    #pragma unroll
    for (int k = 0; k < 8; ++k) cnt[k] = 0;

    #pragma unroll 2
    for (int j = 0; j < TCHUNK; ++j) {
        float4 c0 = scoef[3*j+0];                    // uniform ds_read_b128
        float4 c1 = scoef[3*j+1];
        float2 c2 = *(const float2*)&scoef[3*j+2];   // uniform ds_read_b64

        #pragma unroll
        for (int k = 0; k < 8; ++k) {
            float u = fmaf(c0.x, px[k], fmaf(c0.y, py[k], c0.z));
            float v = fmaf(c0.w, px[k], fmaf(c1.x, py[k], c1.y));
            float t = fmaf(c1.z, px[k], fmaf(c1.w, py[k], fmaf(c2.x, pz[k], c2.y)));
            float w = 1.0f - (u + v);
            float m = fminf(fminf(fminf(u, v), t), w);   // v_min3 + v_min
            cnt[k] += __float_as_int(m) >> 31;           // -1 per miss (ashr+add)
        }
    }
    if (live) {
        #pragma unroll
        for (int k = 0; k < 8; ++k)
            atomicAdd(&out[p0 + k], (float)(TCHUNK + cnt[k]));  // hits = chunk - misses
    }
}

extern "C" void kernel_launch(void* const* d_in, const int* in_sizes, int n_in,
                              void* d_out, int out_size, void* d_ws, size_t ws_size,
                              hipStream_t stream) {
    const float* pts = (const float*)d_in[0];   // [B,N,3]
    const float* v1  = (const float*)d_in[1];   // [F,3]
    const float* v2  = (const float*)d_in[2];
    const float* v3  = (const float*)d_in[3];
    float* out = (float*)d_out;                  // [B,N] counts
    int npts = in_sizes[0] / 3;                  // 65536
    int F    = in_sizes[1] / 3;                  // 2048

    float4* coef = (float4*)d_ws;                // 3*F float4 = 96 KB

    // Output must be zeroed every call (harness poisons once, atomics accumulate).
    hipMemsetAsync(d_out, 0, (size_t)out_size * sizeof(float), stream);

    mt_precompute<<<dim3((F + 255) / 256), dim3(256), 0, stream>>>(v1, v2, v3, coef, F);

    int tsplit = (F + TCHUNK - 1) / TCHUNK;      // 64 -> 32x64 = 2048 blocks, 8/CU
    int nthreads = (npts + 7) / 8;               // 8192 threads, 8 points each
    dim3 grid((nthreads + 255) / 256, tsplit);
    mt_count8<<<grid, dim3(256), 0, stream>>>(coef, pts, out, npts, F);
}

// Round 6
// 68.360 us; speedup vs baseline: 1.8581x; 1.8581x over previous
//
#include <hip/hip_runtime.h>

#define MT_EPS 1e-8f
#define TCHUNK 32   // triangles per LDS-staged chunk (48B each)

// Per-triangle precompute: fold f=1/det, v1 offset, validity, and EPS into
// 10 affine coefficients (3x float4 = 48B stride):
//   u  = cu . (px,py,1)
//   v  = cv . (px,py,1)
//   tm = t-EPS = ct . (px,py,pz,1)     (hit test: tm >= 0)
//   w  = 1-(u+v) computed in-kernel
// Layout: c0 = (cu_x, cu_y, cu_0, cv_x)
//         c1 = (cv_y, cv_0, ct_x, ct_y)
//         c2 = (ct_z, ct_0-EPS, pad, pad)
__global__ __launch_bounds__(256) void mt_precompute(
    const float* __restrict__ v1, const float* __restrict__ v2,
    const float* __restrict__ v3, float4* __restrict__ coef, int F)
{
    int f = blockIdx.x * 256 + threadIdx.x;
    if (f >= F) return;
    float v1x = v1[3*f+0], v1y = v1[3*f+1], v1z = v1[3*f+2];
    float v2x = v2[3*f+0], v2y = v2[3*f+1], v2z = v2[3*f+2];
    float v3x = v3[3*f+0], v3y = v3[3*f+1], v3z = v3[3*f+2];
    float e1x = v2x - v1x, e1y = v2y - v1y, e1z = v2z - v1z;
    float e2x = v3x - v1x, e2y = v3y - v1y, e2z = v3z - v1z;
    float hx = -e2y, hy = e2x;                           // h = cross((0,0,1), e2)
    float a = e1x * hx + e1y * hy;                       // determinant
    float fi = (fabsf(a) > MT_EPS) ? (1.0f / a) : 0.0f;  // invalid -> zero coefs -> tm=-EPS -> miss
    float cux = fi * hx, cuy = fi * hy;
    float cu0 = -(v1x * cux + v1y * cuy);
    float cvx = fi * e1y, cvy = -fi * e1x;
    float cv0 = -(v1x * cvx + v1y * cvy);
    float nx = e1y * e2z - e1z * e2y;
    float ny = e1z * e2x - e1x * e2z;
    float nz = e1x * e2y - e1y * e2x;
    float ctx = fi * nx, cty = fi * ny, ctz = fi * nz;
    float ct0 = -(v1x * ctx + v1y * cty + v1z * ctz) - MT_EPS;
    coef[3*f+0] = make_float4(cux, cuy, cu0, cvx);
    coef[3*f+1] = make_float4(cvy, cv0, ctx, cty);
    coef[3*f+2] = make_float4(ctz, ct0, 0.0f, 0.0f);
}

// Stage 1: 8 points/thread, chunks of TCHUNK triangles staged in LDS.
// NO ATOMICS (R5: device-scope atomicAdd = 32B write-through to HBM, 64
// serialized RMWs/address -> 121us). Per-slice counts <= 2048 fit ushort:
// 8 counts pack into one uint4 -> single coalesced 16B store per thread.
// Per test: 7 FMA + add + sub + min3 + min + ashr + add = 13 VALU.
// Miss-count trick: cnt += sign(m) (-1 per miss); hits = tested + cnt.
__global__ __launch_bounds__(256) void mt_count8(
    const float4* __restrict__ coef, const float* __restrict__ pts,
    unsigned short* __restrict__ partial, int npts, int F,
    int nchunks, int tsplit)
{
    __shared__ float4 scoef[TCHUNK * 3];   // 1.5 KB

    int tid = blockIdx.x * 256 + threadIdx.x;
    int p0 = tid * 8;
    bool full = (p0 + 7 < npts);

    float px[8], py[8], pz[8];
    if (full) {
        const float4* pv = (const float4*)(pts + (size_t)p0 * 3);
        float4 a = pv[0], b = pv[1], c = pv[2];
        float4 d = pv[3], e = pv[4], g = pv[5];
        px[0]=a.x; py[0]=a.y; pz[0]=a.z;
        px[1]=a.w; py[1]=b.x; pz[1]=b.y;
        px[2]=b.z; py[2]=b.w; pz[2]=c.x;
        px[3]=c.y; py[3]=c.z; pz[3]=c.w;
        px[4]=d.x; py[4]=d.y; pz[4]=d.z;
        px[5]=d.w; py[5]=e.x; pz[5]=e.y;
        px[6]=e.z; py[6]=e.w; pz[6]=g.x;
        px[7]=g.y; py[7]=g.z; pz[7]=g.w;
    } else {
        #pragma unroll
        for (int k = 0; k < 8; ++k) {
            int p = p0 + k;
            bool ok = (p < npts);
            px[k] = ok ? pts[3*p+0] : 0.0f;
            py[k] = ok ? pts[3*p+1] : 0.0f;
            pz[k] = ok ? pts[3*p+2] : 0.0f;
        }
    }

    int cnt[8];
    #pragma unroll
    for (int k = 0; k < 8; ++k) cnt[k] = 0;
    int tested = 0;

    for (int ch = blockIdx.y; ch < nchunks; ch += tsplit) {
        if (tested) __syncthreads();           // protect LDS reuse
        if (threadIdx.x < TCHUNK * 3) {
            int gidx = ch * (TCHUNK * 3) + threadIdx.x;
            scoef[threadIdx.x] = (gidx < 3 * F) ? coef[gidx]
                                                : make_float4(0.f, 0.f, 0.f, 0.f);
        }
        __syncthreads();

        #pragma unroll 2
        for (int j = 0; j < TCHUNK; ++j) {
            float4 c0 = scoef[3*j+0];                    // uniform ds_read_b128 (broadcast)
            float4 c1 = scoef[3*j+1];
            float2 c2 = *(const float2*)&scoef[3*j+2];   // uniform ds_read_b64

            #pragma unroll
            for (int k = 0; k < 8; ++k) {
                float u = fmaf(c0.x, px[k], fmaf(c0.y, py[k], c0.z));
                float v = fmaf(c0.w, px[k], fmaf(c1.x, py[k], c1.y));
                float t = fmaf(c1.z, px[k], fmaf(c1.w, py[k], fmaf(c2.x, pz[k], c2.y)));
                float w = 1.0f - (u + v);
                float m = fminf(fminf(fminf(u, v), t), w);   // v_min3 + v_min
                cnt[k] += __float_as_int(m) >> 31;           // -1 per miss
            }
        }
        tested += TCHUNK;   // zero-pad tris count as tested+missed: net 0
    }

    // hits = tested + cnt[k]  (in [0, F] -> fits ushort)
    unsigned short* dst = partial + (size_t)blockIdx.y * npts + p0;
    if (full) {
        uint4 o;
        o.x = (unsigned)(tested + cnt[0]) | ((unsigned)(tested + cnt[1]) << 16);
        o.y = (unsigned)(tested + cnt[2]) | ((unsigned)(tested + cnt[3]) << 16);
        o.z = (unsigned)(tested + cnt[4]) | ((unsigned)(tested + cnt[5]) << 16);
        o.w = (unsigned)(tested + cnt[6]) | ((unsigned)(tested + cnt[7]) << 16);
        *(uint4*)dst = o;                      // one coalesced 16B store
    } else {
        for (int k = 0; k < 8 && p0 + k < npts; ++k)
            dst[k] = (unsigned short)(tested + cnt[k]);
    }
}

// Stage 2: out[p] = sum over slices of partial[y][p]. 4 points/thread,
// coalesced uint2 loads; overwrites every out element (no memset needed).
__global__ __launch_bounds__(256) void mt_reduce(
    const unsigned short* __restrict__ partial, float* __restrict__ out,
    int npts, int tsplit)
{
    int q = blockIdx.x * 256 + threadIdx.x;
    int p = q * 4;
    if (p >= npts) return;
    if (p + 3 < npts) {
        int s0 = 0, s1 = 0, s2 = 0, s3 = 0;
        for (int y = 0; y < tsplit; ++y) {
            uint2 v = *(const uint2*)(partial + (size_t)y * npts + p);
            s0 += v.x & 0xffff; s1 += v.x >> 16;
            s2 += v.y & 0xffff; s3 += v.y >> 16;
        }
        *(float4*)(out + p) = make_float4((float)s0, (float)s1, (float)s2, (float)s3);
    } else {
        for (int k = 0; k < 4 && p + k < npts; ++k) {
            int s = 0;
            for (int y = 0; y < tsplit; ++y) s += partial[(size_t)y * npts + p + k];
            out[p + k] = (float)s;
        }
    }
}

extern "C" void kernel_launch(void* const* d_in, const int* in_sizes, int n_in,
                              void* d_out, int out_size, void* d_ws, size_t ws_size,
                              hipStream_t stream) {
    const float* pts = (const float*)d_in[0];   // [B,N,3]
    const float* v1  = (const float*)d_in[1];   // [F,3]
    const float* v2  = (const float*)d_in[2];
    const float* v3  = (const float*)d_in[3];
    float* out = (float*)d_out;                  // [B,N] counts
    int npts = in_sizes[0] / 3;                  // 65536
    int F    = in_sizes[1] / 3;                  // 2048

    float4* coef = (float4*)d_ws;                // 3*F float4 = 96 KB
    size_t coefBytes = (size_t)3 * F * sizeof(float4);
    unsigned short* partial = (unsigned short*)((char*)d_ws + coefBytes);

    int nchunks = (F + TCHUNK - 1) / TCHUNK;     // 64
    // Adaptive slice count: fit partial buffer (tsplit * npts ushorts) in ws.
    size_t avail = (ws_size > coefBytes) ? ws_size - coefBytes : 0;
    int maxsplit = (int)(avail / ((size_t)npts * sizeof(unsigned short)));
    int tsplit = (nchunks < maxsplit) ? nchunks : maxsplit;
    if (tsplit < 1) tsplit = 1;                  // (needs 128KB; ws had >=128KB in prior rounds)

    mt_precompute<<<dim3((F + 255) / 256), dim3(256), 0, stream>>>(v1, v2, v3, coef, F);

    int nthreads = (npts + 7) / 8;               // 8192 threads, 8 points each
    dim3 grid1((nthreads + 255) / 256, tsplit);  // 32 x 64 = 2048 blocks -> 8/CU
    mt_count8<<<grid1, dim3(256), 0, stream>>>(coef, pts, partial, npts, F, nchunks, tsplit);

    int nq = (npts + 3) / 4;                     // 16384 threads
    mt_reduce<<<dim3((nq + 255) / 256), dim3(256), 0, stream>>>(partial, out, npts, tsplit);
}